// Round 12
// baseline (3685.380 us; speedup 1.0000x reference)
//
#include <hip/hip_runtime.h>

#define B_ 64
#define T_ 4096
#define D_ 256
#define N_ 64

typedef float f32x16 __attribute__((ext_vector_type(16)));

// ---------------- misc: lens + trans copy ----------------
__global__ __launch_bounds__(64) void k_misc(const unsigned char* __restrict__ mask,
                                             const float* __restrict__ trans,
                                             float* __restrict__ out_lens,
                                             float* __restrict__ out_trans,
                                             int* __restrict__ lens_i) {
  int blk = blockIdx.x, lane = threadIdx.x;
  if (blk < B_) {
    int probe = (int)mask[0] + (int)mask[1] + (int)mask[2] + (int)mask[3];
    int cnt = 0;
    if (probe >= 2) {
      const unsigned char* row = mask + (size_t)blk * T_;
      for (int i = lane; i < T_; i += 64) cnt += row[i] ? 1 : 0;
    } else {
      const int* rowi = (const int*)mask + (size_t)blk * T_;
      for (int i = lane; i < T_; i += 64) cnt += rowi[i] ? 1 : 0;
    }
    #pragma unroll
    for (int off = 32; off > 0; off >>= 1) cnt += __shfl_down(cnt, off, 64);
    if (lane == 0) { out_lens[blk] = (float)cnt; lens_i[blk] = cnt; }
  } else {
    int base = (blk - B_) * 1024;
    for (int i = lane; i < 1024; i += 64) out_trans[base + i] = trans[base + i];
  }
}

// ---------------- projection: pot = x@W + b (+ boundaries), LDS-staged x ----------
// (r5 version, proven ~55us)
__global__ __launch_bounds__(256, 2) void k_gemm(const float* __restrict__ x,
                                                 const float* __restrict__ W,
                                                 const float* __restrict__ bias,
                                                 const float* __restrict__ lb,
                                                 const float* __restrict__ rb,
                                                 float* __restrict__ pot) {
  __shared__ float xs[64 * D_];            // 64 KB
  int tid = threadIdx.x;
  int wid = tid >> 6, lane = tid & 63;
  size_t row0 = (size_t)blockIdx.x * 64;

  const float* xb = x + row0 * D_;
  #pragma unroll
  for (int i = 0; i < 16; ++i) {
    int r = wid * 16 + i;
    float4 v = *reinterpret_cast<const float4*>(xb + (size_t)r * D_ + lane * 4);
    *reinterpret_cast<float4*>(&xs[r * D_ + lane * 4]) = v;
  }
  __syncthreads();

  float bv = bias[lane];
  float lbv = lb[lane];
  float rbv = rb[lane];

  float acc[16];
  #pragma unroll
  for (int r = 0; r < 16; ++r) {
    int t = (int)((row0 + wid * 16 + r) & (T_ - 1));
    float a = bv;
    if (t == 0)      a += lbv;
    if (t == T_ - 1) a += rbv;
    acc[r] = a;
  }

  #pragma unroll
  for (int c = 0; c < 4; ++c) {
    float w[64];
    #pragma unroll
    for (int k = 0; k < 64; ++k) w[k] = W[(size_t)(c * 64 + k) * N_ + lane];
    #pragma unroll
    for (int r = 0; r < 16; ++r) {
      const float4* xr = reinterpret_cast<const float4*>(&xs[(wid * 16 + r) * D_ + c * 64]);
      #pragma unroll
      for (int q = 0; q < 16; ++q) {
        float4 xv = xr[q];
        acc[r] += xv.x * w[q * 4 + 0];
        acc[r] += xv.y * w[q * 4 + 1];
        acc[r] += xv.z * w[q * 4 + 2];
        acc[r] += xv.w * w[q * 4 + 3];
      }
    }
  }

  #pragma unroll
  for (int r = 0; r < 16; ++r)
    pot[(row0 + wid * 16 + r) * N_ + lane] = acc[r];
}

// ---------------- phase 1: forward values, TWO chains per wave ----------------
// Same per-batch fp structure as r3 (LDS broadcast + float2 adds + exact max3
// tree). Two independent batches (b, b+32) interleaved at instruction level in
// one wave: B's ds_reads issue under A's LDS latency, A's VALU covers B's
// latency. Shared t2 (trans) registers.
#define FWD_STEP2(TIDX, PRA, PRB)                                                 \
  {                                                                               \
    float potA = PRA;                                                             \
    float potB = PRB;                                                             \
    int tp = (TIDX) + 4; if (tp > T_ - 1) tp = T_ - 1;                            \
    PRA = pbA[(size_t)tp * N_ + lane];                                            \
    PRB = pbB[(size_t)tp * N_ + lane];                                            \
    float mA[64], mB[64];                                                         \
    _Pragma("unroll")                                                             \
    for (int g = 0; g < 16; ++g) {                                                \
      float4 s4 = stA4[g];                                                        \
      float2 ca = make_float2(s4.x, s4.y) + t2[2 * g];                            \
      float2 cb = make_float2(s4.z, s4.w) + t2[2 * g + 1];                        \
      mA[4 * g + 0] = ca.x; mA[4 * g + 1] = ca.y;                                 \
      mA[4 * g + 2] = cb.x; mA[4 * g + 3] = cb.y;                                 \
    }                                                                             \
    _Pragma("unroll")                                                             \
    for (int g = 0; g < 16; ++g) {                                                \
      float4 s4 = stB4[g];                                                        \
      float2 ca = make_float2(s4.x, s4.y) + t2[2 * g];                            \
      float2 cb = make_float2(s4.z, s4.w) + t2[2 * g + 1];                        \
      mB[4 * g + 0] = ca.x; mB[4 * g + 1] = ca.y;                                 \
      mB[4 * g + 2] = cb.x; mB[4 * g + 3] = cb.y;                                 \
    }                                                                             \
    float r1A[22], r1B[22];                                                       \
    _Pragma("unroll")                                                             \
    for (int i = 0; i < 21; ++i) {                                                \
      r1A[i] = fmaxf(fmaxf(mA[3 * i], mA[3 * i + 1]), mA[3 * i + 2]);             \
      r1B[i] = fmaxf(fmaxf(mB[3 * i], mB[3 * i + 1]), mB[3 * i + 2]);             \
    }                                                                             \
    r1A[21] = mA[63]; r1B[21] = mB[63];                                           \
    float r2A[8], r2B[8];                                                         \
    _Pragma("unroll")                                                             \
    for (int i = 0; i < 7; ++i) {                                                 \
      r2A[i] = fmaxf(fmaxf(r1A[3 * i], r1A[3 * i + 1]), r1A[3 * i + 2]);          \
      r2B[i] = fmaxf(fmaxf(r1B[3 * i], r1B[3 * i + 1]), r1B[3 * i + 2]);          \
    }                                                                             \
    r2A[7] = r1A[21]; r2B[7] = r1B[21];                                           \
    float bestA = fmaxf(fmaxf(fmaxf(fmaxf(r2A[0], r2A[1]), r2A[2]),               \
                              fmaxf(fmaxf(r2A[3], r2A[4]), r2A[5])),              \
                        fmaxf(r2A[6], r2A[7]));                                   \
    float bestB = fmaxf(fmaxf(fmaxf(fmaxf(r2B[0], r2B[1]), r2B[2]),               \
                              fmaxf(fmaxf(r2B[3], r2B[4]), r2B[5])),              \
                        fmaxf(r2B[6], r2B[7]));                                   \
    float nsA = potA + bestA;                                                     \
    float nsB = potB + bestB;                                                     \
    stateA = ((TIDX) < lenA) ? nsA : stateA;                                      \
    stateB = ((TIDX) < lenB) ? nsB : stateB;                                      \
    sbA[(size_t)(TIDX) * N_ + lane] = stateA;                                     \
    sbB[(size_t)(TIDX) * N_ + lane] = stateB;                                     \
    __builtin_amdgcn_wave_barrier();                                              \
    stA[lane] = stateA;                                                           \
    stB[lane] = stateB;                                                           \
    __builtin_amdgcn_wave_barrier();                                              \
  }

__global__ __launch_bounds__(64, 1) void k_fwd_states(const float* __restrict__ pot,
                                                      const float* __restrict__ trans,
                                                      const int* __restrict__ lens_i,
                                                      float* __restrict__ states,
                                                      float* __restrict__ fstate) {
  int b0 = blockIdx.x, lane = threadIdx.x;          // handles b0 and b0+32
  int bA = b0, bB = b0 + 32;

  __shared__ float4 stA4[16];
  __shared__ float4 stB4[16];
  float* stA = (float*)stA4;
  float* stB = (float*)stB4;

  float2 t2[32];
  #pragma unroll
  for (int p = 0; p < 32; ++p)
    t2[p] = make_float2(trans[(2 * p) * N_ + lane], trans[(2 * p + 1) * N_ + lane]);

  const float* pbA = pot + (size_t)bA * T_ * N_;
  const float* pbB = pot + (size_t)bB * T_ * N_;
  float* sbA = states + (size_t)bA * T_ * N_;
  float* sbB = states + (size_t)bB * T_ * N_;
  int lenA = lens_i[bA];
  int lenB = lens_i[bB];

  float stateA = pbA[lane];
  float stateB = pbB[lane];
  stA[lane] = stateA;
  stB[lane] = stateB;
  sbA[lane] = stateA;                    // states[t=0]
  sbB[lane] = stateB;
  __builtin_amdgcn_wave_barrier();

  float pA0 = pbA[1 * N_ + lane], pB0 = pbB[1 * N_ + lane];
  float pA1 = pbA[2 * N_ + lane], pB1 = pbB[2 * N_ + lane];
  float pA2 = pbA[3 * N_ + lane], pB2 = pbB[3 * N_ + lane];
  float pA3 = pbA[4 * N_ + lane], pB3 = pbB[4 * N_ + lane];

  int t = 1;
  for (; t + 3 <= T_ - 1; t += 4) {
    FWD_STEP2(t + 0, pA0, pB0);
    FWD_STEP2(t + 1, pA1, pB1);
    FWD_STEP2(t + 2, pA2, pB2);
    FWD_STEP2(t + 3, pA3, pB3);
  }
  // tail: t = 4093, 4094, 4095
  FWD_STEP2(t + 0, pA0, pB0);
  FWD_STEP2(t + 1, pA1, pB1);
  FWD_STEP2(t + 2, pA2, pB2);

  fstate[bA * N_ + lane] = stateA;
  fstate[bB * N_ + lane] = stateB;
}

// ---------------- phase 2: backpointers, block per (b, 4-t group) ----------------
// r2-proven tree body bit-identical; 4 consecutive t per block amortize the
// tcol load (trans L2 traffic /4) while keeping 65k blocks of TLP.
__global__ __launch_bounds__(64, 2) void k_bp(const float* __restrict__ states,
                                              const float* __restrict__ trans,
                                              unsigned char* __restrict__ bp) {
  unsigned idx = blockIdx.x;              // 0 .. B*1024-1
  unsigned b = idx >> 10;
  unsigned c4 = idx & 1023u;
  int lane = threadIdx.x;

  float tcol[64];
  #pragma unroll
  for (int p = 0; p < 64; ++p) tcol[p] = trans[p * N_ + lane];

  int tbase = (int)(c4 * 4 + 1);          // t in tbase .. tbase+3, t <= T_-1

  #pragma unroll
  for (int tt = 0; tt < 4; ++tt) {
    int t = tbase + tt;
    if (t > T_ - 1) break;

    const float* srow = states + ((size_t)b * T_ + (t - 1)) * N_;  // wave-uniform

    float c[64];
    #pragma unroll
    for (int p = 0; p < 64; ++p) c[p] = srow[p] + tcol[p];

    float v1[32]; int i1[32];
    #pragma unroll
    for (int i = 0; i < 32; ++i) {
      bool g = c[2 * i + 1] > c[2 * i];
      v1[i] = g ? c[2 * i + 1] : c[2 * i];
      i1[i] = g ? 2 * i + 1 : 2 * i;
    }
    float v2[16]; int i2[16];
    #pragma unroll
    for (int i = 0; i < 16; ++i) {
      bool g = v1[2 * i + 1] > v1[2 * i];
      v2[i] = g ? v1[2 * i + 1] : v1[2 * i];
      i2[i] = g ? i1[2 * i + 1] : i1[2 * i];
    }
    float v3[8]; int i3[8];
    #pragma unroll
    for (int i = 0; i < 8; ++i) {
      bool g = v2[2 * i + 1] > v2[2 * i];
      v3[i] = g ? v2[2 * i + 1] : v2[2 * i];
      i3[i] = g ? i2[2 * i + 1] : i2[2 * i];
    }
    float v4[4]; int i4[4];
    #pragma unroll
    for (int i = 0; i < 4; ++i) {
      bool g = v3[2 * i + 1] > v3[2 * i];
      v4[i] = g ? v3[2 * i + 1] : v3[2 * i];
      i4[i] = g ? i3[2 * i + 1] : i3[2 * i];
    }
    bool ga = v4[1] > v4[0];
    float va = ga ? v4[1] : v4[0]; int ia = ga ? i4[1] : i4[0];
    bool gb = v4[3] > v4[2];
    float vb = gb ? v4[3] : v4[2]; int ib = gb ? i4[3] : i4[2];
    int bpi = (vb > va) ? ib : ia;

    bp[((size_t)b * T_ + t) * N_ + lane] = (unsigned char)bpi;
  }
}

// ---------------- backtrace: scalar chain (readlane + uniform select) ----------------
__global__ __launch_bounds__(64, 1) void k_bwd(const unsigned char* __restrict__ bp,
                                               const float* __restrict__ fstate,
                                               const int* __restrict__ lens_i,
                                               float* __restrict__ decoded) {
  int b = blockIdx.x, lane = threadIdx.x;

  __shared__ float fv[64];
  __shared__ int sh_tag;
  fv[lane] = fstate[b * N_ + lane];
  __syncthreads();
  if (lane == 0) {
    float best = fv[0]; int tg = 0;
    for (int i = 1; i < 64; ++i) if (fv[i] > best) { best = fv[i]; tg = i; }  // first max
    sh_tag = tg;
  }
  __syncthreads();
  int s_last = __builtin_amdgcn_readfirstlane(sh_tag);
  int len_b = lens_i[b];

  const unsigned char* bpb = bp + (size_t)b * T_ * N_;
  float* dec = decoded + (size_t)b * T_;

  int s_tag = s_last;
  if (lane == 0) dec[T_ - 1] = (float)s_last;

  const int G = 32;
  int bufA[G], bufB[G];
  const int k0 = T_ - 1;
  #pragma unroll
  for (int i = 0; i < G; ++i) bufA[i] = (int)bpb[(size_t)(k0 - i) * N_ + lane];

  const int nrows = T_ - 1;          // 4095
  const int groups = nrows / G;      // 127 full groups + 31 tail

  for (int g = 0; g < groups; ++g) {
    int kn = k0 - G * (g + 1);
    #pragma unroll
    for (int i = 0; i < G; ++i)
      bufB[i] = (kn - i >= 1) ? (int)bpb[(size_t)(kn - i) * N_ + lane] : 0;

    int kbase = k0 - G * g;
    #pragma unroll
    for (int i = 0; i < G; ++i) {
      int k = kbase - i;
      int prev = __builtin_amdgcn_readlane(bufA[i], s_tag);
      int t = k - 1;
      s_tag = (t < len_b - 1) ? prev : s_last;
      if (lane == 0) dec[t] = (float)s_tag;
    }
    #pragma unroll
    for (int i = 0; i < G; ++i) bufA[i] = bufB[i];
  }

  int kbase = k0 - G * groups;
  #pragma unroll
  for (int i = 0; i < G; ++i) {
    int k = kbase - i;
    if (k >= 1) {
      int prev = __builtin_amdgcn_readlane(bufA[i], s_tag);
      int t = k - 1;
      s_tag = (t < len_b - 1) ? prev : s_last;
      if (lane == 0) dec[t] = (float)s_tag;
    }
  }
}

extern "C" void kernel_launch(void* const* d_in, const int* in_sizes, int n_in,
                              void* d_out, int out_size, void* d_ws, size_t ws_size,
                              hipStream_t stream) {
  const float* x            = (const float*)d_in[0];
  const unsigned char* mask = (const unsigned char*)d_in[1];
  const float* W            = (const float*)d_in[2];
  const float* bias         = (const float*)d_in[3];
  const float* trans        = (const float*)d_in[4];
  const float* lb           = (const float*)d_in[5];
  const float* rb           = (const float*)d_in[6];

  float* out         = (float*)d_out;
  float* out_decoded = out;                              // B*T
  float* out_pot     = out + (size_t)B_ * T_;            // B*T*N
  float* out_lens    = out_pot + (size_t)B_ * T_ * N_;   // B
  float* out_trans   = out_lens + B_;                    // N*N

  const size_t bp_bytes   = (size_t)B_ * T_ * N_;        // 16,777,216
  const size_t fstate_off = bp_bytes;
  const size_t lens_off   = fstate_off + (size_t)B_ * N_ * 4;
  const size_t states_off = lens_off + 256;

  unsigned char* bp = (unsigned char*)d_ws;
  float* fstate     = (float*)((char*)d_ws + fstate_off);
  int*   lens_i     = (int*)((char*)d_ws + lens_off);
  float* states     = (float*)((char*)d_ws + states_off);

  k_misc<<<68, 64, 0, stream>>>(mask, trans, out_lens, out_trans, lens_i);
  k_gemm<<<(B_ * T_) / 64, 256, 0, stream>>>(x, W, bias, lb, rb, out_pot);
  k_fwd_states<<<B_ / 2, 64, 0, stream>>>(out_pot, trans, lens_i, states, fstate);
  k_bp<<<B_ * (T_ / 4), 64, 0, stream>>>(states, trans, bp);
  k_bwd<<<B_, 64, 0, stream>>>(bp, fstate, lens_i, out_decoded);
}

// Round 13
// 2214.432 us; speedup vs baseline: 1.6643x; 1.6643x over previous
//
#include <hip/hip_runtime.h>

#define B_ 64
#define T_ 4096
#define D_ 256
#define N_ 64

typedef float f32x16 __attribute__((ext_vector_type(16)));

// ---------------- misc: lens + trans copy ----------------
__global__ __launch_bounds__(64) void k_misc(const unsigned char* __restrict__ mask,
                                             const float* __restrict__ trans,
                                             float* __restrict__ out_lens,
                                             float* __restrict__ out_trans,
                                             int* __restrict__ lens_i) {
  int blk = blockIdx.x, lane = threadIdx.x;
  if (blk < B_) {
    int probe = (int)mask[0] + (int)mask[1] + (int)mask[2] + (int)mask[3];
    int cnt = 0;
    if (probe >= 2) {
      const unsigned char* row = mask + (size_t)blk * T_;
      for (int i = lane; i < T_; i += 64) cnt += row[i] ? 1 : 0;
    } else {
      const int* rowi = (const int*)mask + (size_t)blk * T_;
      for (int i = lane; i < T_; i += 64) cnt += rowi[i] ? 1 : 0;
    }
    #pragma unroll
    for (int off = 32; off > 0; off >>= 1) cnt += __shfl_down(cnt, off, 64);
    if (lane == 0) { out_lens[blk] = (float)cnt; lens_i[blk] = cnt; }
  } else {
    int base = (blk - B_) * 1024;
    for (int i = lane; i < 1024; i += 64) out_trans[base + i] = trans[base + i];
  }
}

// ---------------- projection: pot = x@W + b (+ boundaries), LDS-staged x ----------
// (r5 version, proven ~55us)
__global__ __launch_bounds__(256, 2) void k_gemm(const float* __restrict__ x,
                                                 const float* __restrict__ W,
                                                 const float* __restrict__ bias,
                                                 const float* __restrict__ lb,
                                                 const float* __restrict__ rb,
                                                 float* __restrict__ pot) {
  __shared__ float xs[64 * D_];            // 64 KB
  int tid = threadIdx.x;
  int wid = tid >> 6, lane = tid & 63;
  size_t row0 = (size_t)blockIdx.x * 64;

  const float* xb = x + row0 * D_;
  #pragma unroll
  for (int i = 0; i < 16; ++i) {
    int r = wid * 16 + i;
    float4 v = *reinterpret_cast<const float4*>(xb + (size_t)r * D_ + lane * 4);
    *reinterpret_cast<float4*>(&xs[r * D_ + lane * 4]) = v;
  }
  __syncthreads();

  float bv = bias[lane];
  float lbv = lb[lane];
  float rbv = rb[lane];

  float acc[16];
  #pragma unroll
  for (int r = 0; r < 16; ++r) {
    int t = (int)((row0 + wid * 16 + r) & (T_ - 1));
    float a = bv;
    if (t == 0)      a += lbv;
    if (t == T_ - 1) a += rbv;
    acc[r] = a;
  }

  #pragma unroll
  for (int c = 0; c < 4; ++c) {
    float w[64];
    #pragma unroll
    for (int k = 0; k < 64; ++k) w[k] = W[(size_t)(c * 64 + k) * N_ + lane];
    #pragma unroll
    for (int r = 0; r < 16; ++r) {
      const float4* xr = reinterpret_cast<const float4*>(&xs[(wid * 16 + r) * D_ + c * 64]);
      #pragma unroll
      for (int q = 0; q < 16; ++q) {
        float4 xv = xr[q];
        acc[r] += xv.x * w[q * 4 + 0];
        acc[r] += xv.y * w[q * 4 + 1];
        acc[r] += xv.z * w[q * 4 + 2];
        acc[r] += xv.w * w[q * 4 + 3];
      }
    }
  }

  #pragma unroll
  for (int r = 0; r < 16; ++r)
    pot[(row0 + wid * 16 + r) * N_ + lane] = acc[r];
}

// ---------------- phase 1: forward values, 4-wave cooperative step ----------------
// Wave w owns prev-states p in [16w,16w+16). Per step: 16 readlane (SGPR
// broadcast of this wave's redundant state copy) + 16 add + max3 tree ->
// partial; ds_write -> lgkmcnt(0) -> raw s_barrier (NO vmcnt drain: pot
// prefetch loads survive across barriers) -> 4 ds_read_b32 -> combine ->
// identical state recomputed in every wave. Values bit-exact (same adds,
// fp max exact under any association).
#define RDL(J) (__int_as_float(__builtin_amdgcn_readlane(__float_as_int(state), pb16 + (J))) + tc[J])

#define FWD_STEP(TIDX, PREG)                                                      \
  {                                                                               \
    float pot_t = PREG;                                                           \
    int tp = (TIDX) + 4; if (tp > T_ - 1) tp = T_ - 1;                            \
    PREG = pb[(size_t)tp * N_ + lane];                                            \
    float c0 = RDL(0), c1 = RDL(1), c2 = RDL(2), c3 = RDL(3);                     \
    float c4 = RDL(4), c5 = RDL(5), c6 = RDL(6), c7 = RDL(7);                     \
    float c8 = RDL(8), c9 = RDL(9), c10 = RDL(10), c11 = RDL(11);                 \
    float c12 = RDL(12), c13 = RDL(13), c14 = RDL(14), c15 = RDL(15);             \
    float m0 = fmaxf(fmaxf(c0, c1), c2);                                          \
    float m1 = fmaxf(fmaxf(c3, c4), c5);                                          \
    float m2 = fmaxf(fmaxf(c6, c7), c8);                                          \
    float m3 = fmaxf(fmaxf(c9, c10), c11);                                        \
    float m4 = fmaxf(fmaxf(c12, c13), c14);                                       \
    float pa = fmaxf(fmaxf(fmaxf(m0, m1), m2), fmaxf(fmaxf(m3, m4), c15));        \
    part[(TIDX) & 1][wid][lane] = pa;                                             \
    asm volatile("s_waitcnt lgkmcnt(0)" ::: "memory");                            \
    __builtin_amdgcn_s_barrier();                                                 \
    asm volatile("" ::: "memory");                                                \
    float q0 = part[(TIDX) & 1][0][lane];                                         \
    float q1 = part[(TIDX) & 1][1][lane];                                         \
    float q2 = part[(TIDX) & 1][2][lane];                                         \
    float q3 = part[(TIDX) & 1][3][lane];                                         \
    float best = fmaxf(fmaxf(q0, q1), fmaxf(q2, q3));                             \
    float ns = pot_t + best;                                                      \
    state = ((TIDX) < len_b) ? ns : state;                                        \
    if (wid == ((TIDX) & 3)) sb[(size_t)(TIDX) * N_ + lane] = state;              \
  }

__global__ __launch_bounds__(256, 1) void k_fwd_states(const float* __restrict__ pot,
                                                       const float* __restrict__ trans,
                                                       const int* __restrict__ lens_i,
                                                       float* __restrict__ states,
                                                       float* __restrict__ fstate) {
  __shared__ float part[2][4][64];       // 2 KB, double-buffered partials

  int b = blockIdx.x;
  int tid = threadIdx.x;
  int wid = tid >> 6, lane = tid & 63;
  int pb16 = wid * 16;

  // tc[j] = trans[pb16 + j][lane]  (this wave's 16 prev rows)
  float tc[16];
  #pragma unroll
  for (int j = 0; j < 16; ++j) tc[j] = trans[(size_t)(pb16 + j) * N_ + lane];

  const float* pb = pot + (size_t)b * T_ * N_;
  float* sb = states + (size_t)b * T_ * N_;
  int len_b = lens_i[b];

  float state = pb[lane];               // t=0, redundant copy in all 4 waves
  if (wid == 0) sb[lane] = state;

  float p0 = pb[1 * N_ + lane];
  float p1 = pb[2 * N_ + lane];
  float p2 = pb[3 * N_ + lane];
  float p3 = pb[4 * N_ + lane];

  int t = 1;
  for (; t + 3 <= T_ - 1; t += 4) {
    FWD_STEP(t + 0, p0);
    FWD_STEP(t + 1, p1);
    FWD_STEP(t + 2, p2);
    FWD_STEP(t + 3, p3);
  }
  // tail: t = 4093, 4094, 4095
  FWD_STEP(t + 0, p0);
  FWD_STEP(t + 1, p1);
  FWD_STEP(t + 2, p2);

  if (wid == 0) fstate[b * N_ + lane] = state;
}

// ---------------- phase 2: backpointers, one block per (b,t) (r10, 286us) ----------
__global__ __launch_bounds__(64, 2) void k_bp(const float* __restrict__ states,
                                              const float* __restrict__ trans,
                                              unsigned char* __restrict__ bp) {
  unsigned idx = blockIdx.x;              // 0 .. B*(T-1)-1
  unsigned b = idx / (unsigned)(T_ - 1);
  unsigned t = 1u + idx - b * (unsigned)(T_ - 1);
  int lane = threadIdx.x;

  float tcol[64];
  #pragma unroll
  for (int p = 0; p < 64; ++p) tcol[p] = trans[p * N_ + lane];

  const float* srow = states + ((size_t)b * T_ + (t - 1)) * N_;  // wave-uniform base

  float c[64];
  #pragma unroll
  for (int p = 0; p < 64; ++p) c[p] = srow[p] + tcol[p];

  // first-index argmax tree: right wins only on strictly-greater
  float v1[32]; int i1[32];
  #pragma unroll
  for (int i = 0; i < 32; ++i) {
    bool g = c[2 * i + 1] > c[2 * i];
    v1[i] = g ? c[2 * i + 1] : c[2 * i];
    i1[i] = g ? 2 * i + 1 : 2 * i;
  }
  float v2[16]; int i2[16];
  #pragma unroll
  for (int i = 0; i < 16; ++i) {
    bool g = v1[2 * i + 1] > v1[2 * i];
    v2[i] = g ? v1[2 * i + 1] : v1[2 * i];
    i2[i] = g ? i1[2 * i + 1] : i1[2 * i];
  }
  float v3[8]; int i3[8];
  #pragma unroll
  for (int i = 0; i < 8; ++i) {
    bool g = v2[2 * i + 1] > v2[2 * i];
    v3[i] = g ? v2[2 * i + 1] : v2[2 * i];
    i3[i] = g ? i2[2 * i + 1] : i2[2 * i];
  }
  float v4[4]; int i4[4];
  #pragma unroll
  for (int i = 0; i < 4; ++i) {
    bool g = v3[2 * i + 1] > v3[2 * i];
    v4[i] = g ? v3[2 * i + 1] : v3[2 * i];
    i4[i] = g ? i3[2 * i + 1] : i3[2 * i];
  }
  bool ga = v4[1] > v4[0];
  float va = ga ? v4[1] : v4[0]; int ia = ga ? i4[1] : i4[0];
  bool gb = v4[3] > v4[2];
  float vb = gb ? v4[3] : v4[2]; int ib = gb ? i4[3] : i4[2];
  int bpi = (vb > va) ? ib : ia;

  bp[((size_t)b * T_ + t) * N_ + lane] = (unsigned char)bpi;
}

// ---------------- backtrace: scalar chain (readlane + uniform select) ----------------
__global__ __launch_bounds__(64, 1) void k_bwd(const unsigned char* __restrict__ bp,
                                               const float* __restrict__ fstate,
                                               const int* __restrict__ lens_i,
                                               float* __restrict__ decoded) {
  int b = blockIdx.x, lane = threadIdx.x;

  __shared__ float fv[64];
  __shared__ int sh_tag;
  fv[lane] = fstate[b * N_ + lane];
  __syncthreads();
  if (lane == 0) {
    float best = fv[0]; int tg = 0;
    for (int i = 1; i < 64; ++i) if (fv[i] > best) { best = fv[i]; tg = i; }  // first max
    sh_tag = tg;
  }
  __syncthreads();
  int s_last = __builtin_amdgcn_readfirstlane(sh_tag);
  int len_b = lens_i[b];

  const unsigned char* bpb = bp + (size_t)b * T_ * N_;
  float* dec = decoded + (size_t)b * T_;

  int s_tag = s_last;
  if (lane == 0) dec[T_ - 1] = (float)s_last;

  const int G = 32;
  int bufA[G], bufB[G];
  const int k0 = T_ - 1;
  #pragma unroll
  for (int i = 0; i < G; ++i) bufA[i] = (int)bpb[(size_t)(k0 - i) * N_ + lane];

  const int nrows = T_ - 1;          // 4095
  const int groups = nrows / G;      // 127 full groups + 31 tail

  for (int g = 0; g < groups; ++g) {
    int kn = k0 - G * (g + 1);
    #pragma unroll
    for (int i = 0; i < G; ++i)
      bufB[i] = (kn - i >= 1) ? (int)bpb[(size_t)(kn - i) * N_ + lane] : 0;

    int kbase = k0 - G * g;
    #pragma unroll
    for (int i = 0; i < G; ++i) {
      int k = kbase - i;
      int prev = __builtin_amdgcn_readlane(bufA[i], s_tag);
      int t = k - 1;
      s_tag = (t < len_b - 1) ? prev : s_last;
      if (lane == 0) dec[t] = (float)s_tag;
    }
    #pragma unroll
    for (int i = 0; i < G; ++i) bufA[i] = bufB[i];
  }

  int kbase = k0 - G * groups;
  #pragma unroll
  for (int i = 0; i < G; ++i) {
    int k = kbase - i;
    if (k >= 1) {
      int prev = __builtin_amdgcn_readlane(bufA[i], s_tag);
      int t = k - 1;
      s_tag = (t < len_b - 1) ? prev : s_last;
      if (lane == 0) dec[t] = (float)s_tag;
    }
  }
}

extern "C" void kernel_launch(void* const* d_in, const int* in_sizes, int n_in,
                              void* d_out, int out_size, void* d_ws, size_t ws_size,
                              hipStream_t stream) {
  const float* x            = (const float*)d_in[0];
  const unsigned char* mask = (const unsigned char*)d_in[1];
  const float* W            = (const float*)d_in[2];
  const float* bias         = (const float*)d_in[3];
  const float* trans        = (const float*)d_in[4];
  const float* lb           = (const float*)d_in[5];
  const float* rb           = (const float*)d_in[6];

  float* out         = (float*)d_out;
  float* out_decoded = out;                              // B*T
  float* out_pot     = out + (size_t)B_ * T_;            // B*T*N
  float* out_lens    = out_pot + (size_t)B_ * T_ * N_;   // B
  float* out_trans   = out_lens + B_;                    // N*N

  const size_t bp_bytes   = (size_t)B_ * T_ * N_;        // 16,777,216
  const size_t fstate_off = bp_bytes;
  const size_t lens_off   = fstate_off + (size_t)B_ * N_ * 4;
  const size_t states_off = lens_off + 256;

  unsigned char* bp = (unsigned char*)d_ws;
  float* fstate     = (float*)((char*)d_ws + fstate_off);
  int*   lens_i     = (int*)((char*)d_ws + lens_off);
  float* states     = (float*)((char*)d_ws + states_off);

  k_misc<<<68, 64, 0, stream>>>(mask, trans, out_lens, out_trans, lens_i);
  k_gemm<<<(B_ * T_) / 64, 256, 0, stream>>>(x, W, bias, lb, rb, out_pot);
  k_fwd_states<<<B_, 256, 0, stream>>>(out_pot, trans, lens_i, states, fstate);
  k_bp<<<B_ * (T_ - 1), 64, 0, stream>>>(states, trans, bp);
  k_bwd<<<B_, 64, 0, stream>>>(bp, fstate, lens_i, out_decoded);
}